// Round 1
// baseline (110.143 us; speedup 1.0000x reference)
//
#include <hip/hip_runtime.h>
#include <math.h>

#define T_TOK 4096
#define D_DIM 2048
#define E_EXP 8

struct TokRec { int e0, e1; float g0, g1; };

// ---------------- Kernel 1: gating (logits -> softmax -> top2) --------------
// One wave (64 lanes) per token. fp64 accumulation to match a high-precision
// reference ordering as closely as possible.
__global__ __launch_bounds__(256) void gating_kernel(const float* __restrict__ x,
                                                     const float* __restrict__ Wg,
                                                     TokRec* __restrict__ recs) {
    const int wave = threadIdx.x >> 6;
    const int lane = threadIdx.x & 63;
    const int t = blockIdx.x * 4 + wave;
    const float* xr = x + (size_t)t * D_DIM;

    double acc[E_EXP];
#pragma unroll
    for (int e = 0; e < E_EXP; ++e) acc[e] = 0.0;

#pragma unroll
    for (int i = 0; i < D_DIM / 256; ++i) {
        const int d = i * 256 + lane * 4;
        const float4 xv = *reinterpret_cast<const float4*>(xr + d);
#pragma unroll
        for (int j = 0; j < 4; ++j) {
            const float xs = (j == 0) ? xv.x : (j == 1) ? xv.y : (j == 2) ? xv.z : xv.w;
            const float4 w0 = *reinterpret_cast<const float4*>(Wg + (size_t)(d + j) * E_EXP);
            const float4 w1 = *reinterpret_cast<const float4*>(Wg + (size_t)(d + j) * E_EXP + 4);
            acc[0] += (double)xs * (double)w0.x;
            acc[1] += (double)xs * (double)w0.y;
            acc[2] += (double)xs * (double)w0.z;
            acc[3] += (double)xs * (double)w0.w;
            acc[4] += (double)xs * (double)w1.x;
            acc[5] += (double)xs * (double)w1.y;
            acc[6] += (double)xs * (double)w1.z;
            acc[7] += (double)xs * (double)w1.w;
        }
    }
    // wave-wide reduction of the 8 partial dots
#pragma unroll
    for (int e = 0; e < E_EXP; ++e) {
        double v = acc[e];
#pragma unroll
        for (int off = 32; off > 0; off >>= 1) v += __shfl_xor(v, off, 64);
        acc[e] = v;
    }
    if (lane == 0) {
        double m = acc[0];
#pragma unroll
        for (int e = 1; e < E_EXP; ++e) m = (acc[e] > m) ? acc[e] : m;
        double Z = 0.0;
#pragma unroll
        for (int e = 0; e < E_EXP; ++e) Z += exp(acc[e] - m);
        // top-1: strict > keeps lowest index on ties (lax.top_k stable order)
        int e0 = 0;
#pragma unroll
        for (int e = 1; e < E_EXP; ++e) if (acc[e] > acc[e0]) e0 = e;
        int e1 = (e0 == 0) ? 1 : 0;
#pragma unroll
        for (int e = 0; e < E_EXP; ++e) if (e != e0 && acc[e] > acc[e1]) e1 = e;
        TokRec r;
        r.e0 = e0; r.e1 = e1;
        r.g0 = (float)(exp(acc[e0] - m) / Z);
        r.g1 = (float)(exp(acc[e1] - m) / Z);
        recs[t] = r;
    }
}

// ---------------- Kernel 2: single-block scan -> positions ------------------
// 256 threads x 16 tokens each. Per-expert counts packed as 8x16-bit fields
// in a uint4; Hillis-Steele inclusive scan; then deterministic scatter of
// (token, gate) into srcmap/gatemap at the cumsum positions.
__global__ __launch_bounds__(256) void scan_kernel(const TokRec* __restrict__ recs,
                                                   int* __restrict__ srcmap,
                                                   float* __restrict__ gatemap,
                                                   float* __restrict__ loads_out) {
    __shared__ uint4 sb[256];
    __shared__ int offlds[256 * 8];
    const int tid = threadIdx.x;

    // default: empty slots
    for (int i = tid; i < E_EXP * T_TOK; i += 256) srcmap[i] = -1;

    // local counts as 8x8-bit fields (max 32 per field, no overflow)
    const int t0 = tid * 16;
    unsigned long long c = 0ULL;
    for (int k = 0; k < 16; ++k) {
        TokRec r = recs[t0 + k];
        c += 1ULL << (r.e0 * 8);
        c += 1ULL << (r.e1 * 8);
    }
    uint4 v;
    v.x = (unsigned)((c       ) & 0xFF) | ((unsigned)((c >>  8) & 0xFF) << 16);
    v.y = (unsigned)((c >> 16 ) & 0xFF) | ((unsigned)((c >> 24) & 0xFF) << 16);
    v.z = (unsigned)((c >> 32 ) & 0xFF) | ((unsigned)((c >> 40) & 0xFF) << 16);
    v.w = (unsigned)((c >> 48 ) & 0xFF) | ((unsigned)((c >> 56) & 0xFF) << 16);
    const uint4 own = v;
    sb[tid] = v;
    for (int d = 1; d < 256; d <<= 1) {
        __syncthreads();
        uint4 o = make_uint4(0u, 0u, 0u, 0u);
        if (tid >= d) o = sb[tid - d];
        __syncthreads();
        v.x += o.x; v.y += o.y; v.z += o.z; v.w += o.w;
        sb[tid] = v;
    }
    __syncthreads();
    const uint4 tot = sb[255];

    // exclusive prefix for this thread
    offlds[tid * 8 + 0] = (int)((v.x - own.x) & 0xFFFF);
    offlds[tid * 8 + 1] = (int)((v.x - own.x) >> 16);
    offlds[tid * 8 + 2] = (int)((v.y - own.y) & 0xFFFF);
    offlds[tid * 8 + 3] = (int)((v.y - own.y) >> 16);
    offlds[tid * 8 + 4] = (int)((v.z - own.z) & 0xFFFF);
    offlds[tid * 8 + 5] = (int)((v.z - own.z) >> 16);
    offlds[tid * 8 + 6] = (int)((v.w - own.w) & 0xFFFF);
    offlds[tid * 8 + 7] = (int)((v.w - own.w) >> 16);

    if (tid < 8) {
        unsigned comp = (tid < 2) ? tot.x : (tid < 4) ? tot.y : (tid < 6) ? tot.z : tot.w;
        unsigned val = (tid & 1) ? (comp >> 16) : (comp & 0xFFFF);
        loads_out[tid] = (float)val;   // loads output written as float32
    }

    // scatter tokens (ascending order within thread keeps cumsum semantics)
    const int obase = tid * 8;
    for (int k = 0; k < 16; ++k) {
        TokRec r = recs[t0 + k];
        const int tok = t0 + k;
        int d0 = offlds[obase + r.e0]++;
        srcmap[r.e0 * T_TOK + d0] = tok;
        gatemap[r.e0 * T_TOK + d0] = r.g0;
        int d1 = offlds[obase + r.e1]++;
        srcmap[r.e1 * T_TOK + d1] = tok;
        gatemap[r.e1 * T_TOK + d1] = r.g1;
    }
}

// ---------------- Kernel 3: full out_data fill + tags -----------------------
// One block per output row (e*T + r); 256 threads x 8 floats = 2048.
__global__ __launch_bounds__(256) void scatter_kernel(const float* __restrict__ x,
                                                      const int* __restrict__ srcmap,
                                                      const float* __restrict__ gatemap,
                                                      float* __restrict__ out_data,
                                                      float* __restrict__ out_tags) {
    const int row = blockIdx.x;
    const int tid = threadIdx.x;
    const int src = srcmap[row];
    float* orow = out_data + (size_t)row * D_DIM;
    if (tid == 0) out_tags[row] = (float)src;   // tags written as float32
    const int base = tid * 8;
    if (src < 0) {
        const float4 z = make_float4(0.f, 0.f, 0.f, 0.f);
        *reinterpret_cast<float4*>(orow + base) = z;
        *reinterpret_cast<float4*>(orow + base + 4) = z;
    } else {
        const float g = gatemap[row];
        const float* xr = x + (size_t)src * D_DIM;
        float4 a = *reinterpret_cast<const float4*>(xr + base);
        float4 b = *reinterpret_cast<const float4*>(xr + base + 4);
        a.x *= g; a.y *= g; a.z *= g; a.w *= g;
        b.x *= g; b.y *= g; b.z *= g; b.w *= g;
        *reinterpret_cast<float4*>(orow + base) = a;
        *reinterpret_cast<float4*>(orow + base + 4) = b;
    }
}

extern "C" void kernel_launch(void* const* d_in, const int* in_sizes, int n_in,
                              void* d_out, int out_size, void* d_ws, size_t ws_size,
                              hipStream_t stream) {
    const float* x  = (const float*)d_in[0];
    const float* Wg = (const float*)d_in[1];

    float* out       = (float*)d_out;
    float* out_data  = out;
    float* out_tags  = out + (size_t)E_EXP * T_TOK * D_DIM;
    float* out_loads = out_tags + E_EXP * T_TOK;

    char* ws = (char*)d_ws;
    TokRec* recs   = (TokRec*)ws;                          // 64 KiB
    int*    srcmap = (int*)(ws + 65536);                   // 128 KiB
    float*  gatemap = (float*)(ws + 65536 + 131072);       // 128 KiB

    gating_kernel<<<T_TOK / 4, 256, 0, stream>>>(x, Wg, recs);
    scan_kernel<<<1, 256, 0, stream>>>(recs, srcmap, gatemap, out_loads);
    scatter_kernel<<<E_EXP * T_TOK, 256, 0, stream>>>(x, srcmap, gatemap, out_data, out_tags);
}